// Round 1
// 206.793 us; speedup vs baseline: 1.0403x; 1.0403x over previous
//
#include <hip/hip_runtime.h>
#include <hip/hip_bf16.h>

#define N_NODES 100000
#define N_EDGES 1600000
#define D 64
#define NEG_SLOPE 0.2f

#define BSHIFT 10                                  // bucket = dst >> 10
#define BNODES 1024                                // nodes per bucket
#define NBUCK ((N_NODES + BNODES - 1) >> BSHIFT)   // 98
#define BUCKET_CAP 17408   // mean 16384, sigma ~127 -> 8-sigma headroom
#define P1_EPB 4096        // edges per binning block
#define P1_T 512
#define P1_IT (P1_EPB / P1_T)                      // 8 edges/thread

// ---------------------------------------------------------------------------
// Pass 1: bin edges by coarse dst bucket, LDS-staged so ALL global writes are
// coalesced runs (direct scatter wrote 100 MB of dirty partial lines for a
// 12.8 MB array -- write-line-granularity bound). Entry: {x = (src<<15)|wcode
// (bf16 weight, sign dropped), y = dst}. 512 threads: fewer serial
// iterations/thread, more waves to hide LDS-atomic latency.
// segment_max skipped: softmax is shift-invariant and |e| <= |a0|+|a1| is
// tiny, so exp() cannot overflow -- identical math to the reference.
// ---------------------------------------------------------------------------
__global__ __launch_bounds__(P1_T) void binning_kernel(
    const float2* __restrict__ rel, const float* __restrict__ attn_e,
    const int* __restrict__ src, const int* __restrict__ dst,
    int* __restrict__ bucket_cursor, uint2* __restrict__ binned)
{
    __shared__ uint2 staged1[P1_EPB];   // arrival order      (32 KB)
    __shared__ uint2 staged2[P1_EPB];   // bucket-sorted      (32 KB)
    __shared__ int cnt[NBUCK];
    __shared__ int excl[NBUCK];
    __shared__ int chunkbase[NBUCK];

    int tid = threadIdx.x;
    int e0 = blockIdx.x * P1_EPB;
    int n = min(P1_EPB, N_EDGES - e0);

    for (int b = tid; b < NBUCK; b += P1_T) cnt[b] = 0;
    __syncthreads();

    float a0 = attn_e[0], a1 = attn_e[1];

    int myslot[P1_IT];                  // fixed-index -> stays in VGPRs
    #pragma unroll
    for (int j = 0; j < P1_IT; ++j) {
        int i = tid + j * P1_T;
        if (i < n) {
            int e = e0 + i;
            float2 r = rel[e];
            float sc = r.x * a0 + r.y * a1;
            sc = (sc > 0.f) ? sc : NEG_SLOPE * sc;
            float ev = __expf(sc);
            unsigned u = __float_as_uint(ev) + 0x8000u;     // RNE to bf16
            unsigned wcode = (u >> 16) & 0x7FFFu;           // drop sign (ev>0)
            unsigned s = (unsigned)src[e];
            unsigned d = (unsigned)dst[e];
            staged1[i] = make_uint2((s << 15) | wcode, d);
            myslot[j] = atomicAdd(&cnt[d >> BSHIFT], 1);    // local ticket
        }
    }
    __syncthreads();
    if (tid == 0) {                     // 98-entry serial scan: trivial
        int run = 0;
        for (int b = 0; b < NBUCK; ++b) { excl[b] = run; run += cnt[b]; }
    }
    __syncthreads();
    #pragma unroll
    for (int j = 0; j < P1_IT; ++j) {   // LDS scatter into bucket order
        int i = tid + j * P1_T;
        if (i < n) {
            uint2 v = staged1[i];
            staged2[excl[v.y >> BSHIFT] + myslot[j]] = v;
        }
    }
    if (tid < NBUCK)                    // reserve contiguous global chunks
        chunkbase[tid] = atomicAdd(&bucket_cursor[tid], cnt[tid]);
    __syncthreads();
    for (int i = tid; i < n; i += P1_T) {  // coalesced runs per bucket chunk
        uint2 v = staged2[i];
        int b = (int)(v.y >> BSHIFT);
        binned[(size_t)b * BUCKET_CAP + chunkbase[b] + (i - excl[b])] = v;
    }
}

// ---------------------------------------------------------------------------
// Pass 2: one block per bucket, 1024 threads. LDS histogram -> LDS scan ->
// write offsets -> LDS scatter of packed values -> coalesced flush into the
// bucket's contiguous CSR range.
// ---------------------------------------------------------------------------
__global__ __launch_bounds__(1024) void csr_kernel(
    const int* __restrict__ bucket_cursor, const uint2* __restrict__ binned,
    int* __restrict__ offsets, unsigned* __restrict__ edata)
{
    __shared__ unsigned vals[BUCKET_CAP];   // 69.6 KB
    __shared__ int hist[BNODES];
    __shared__ int nexcl[BNODES];
    __shared__ int cur[BNODES];
    __shared__ int bc[NBUCK];
    __shared__ int base_sh;

    int b = blockIdx.x;
    int tid = threadIdx.x;

    if (tid < NBUCK) bc[tid] = bucket_cursor[tid];
    hist[tid] = 0;                      // 1024 threads cover BNODES exactly
    cur[tid] = 0;
    __syncthreads();
    if (tid == 0) {
        int s = 0;
        for (int i = 0; i < b; ++i) s += bc[i];
        base_sh = s;
    }
    __syncthreads();
    int count = bc[b];
    int base = base_sh;
    const uint2* bin = binned + (size_t)b * BUCKET_CAP;

    for (int i = tid; i < count; i += 1024)
        atomicAdd(&hist[bin[i].y & (BNODES - 1)], 1);
    __syncthreads();

    // inclusive Hillis-Steele over 1024 bins, one bin per thread
    int h = hist[tid];
    nexcl[tid] = h;
    __syncthreads();
    for (int d = 1; d < BNODES; d <<= 1) {
        int u = (tid >= d) ? nexcl[tid - d] : 0;
        __syncthreads();
        nexcl[tid] += u;
        __syncthreads();
    }
    int excl = nexcl[tid] - h;          // exclusive prefix
    __syncthreads();
    nexcl[tid] = excl;
    __syncthreads();

    int node = (b << BSHIFT) + tid;
    if (node < N_NODES) offsets[node] = base + excl;
    if (b == NBUCK - 1 && tid == 0) offsets[N_NODES] = N_EDGES;

    for (int i = tid; i < count; i += 1024) {     // LDS scatter
        uint2 e = bin[i];
        int d = e.y & (BNODES - 1);
        int t = atomicAdd(&cur[d], 1);
        vals[nexcl[d] + t] = e.x;
    }
    __syncthreads();
    for (int i = tid; i < count; i += 1024)       // coalesced flush
        edata[base + i] = vals[i];
}

// ---------------------------------------------------------------------------
// FUSED GEMM, now on the MATRIX pipe (prev version: pure-VALU fp32 dot
// products, MfmaUtil=0, 47.9us for a kernel with an 11us memory floor).
// Split-precision bf16 MFMA: x = hi + lo (two RNE bf16 extractions), then
// A@B ~= Ahi@Bhi + Alo@Bhi + Ahi@Blo -- only the ~2^-18-relative Alo@Blo
// term is dropped, so fp32-grade accuracy with 3 MFMAs per K-step.
// Convention = learn_hip m89/m91-verified gemm_bt: A=feat[M][K],
// B=W[N][K] (torch Linear weight IS B^T layout); frag: A lane&15=row,
// B lane&15=col, k=(lane>>4)*8+j; C: col=lane&15, row=(lane>>4)*4+reg.
// 512 thr = 8 waves x 16 rows = 128 rows/block. No LDS, no barriers;
// W fragments re-read from L2 per block (~100 MB aggregate, cheap).
// ---------------------------------------------------------------------------
typedef __attribute__((ext_vector_type(8))) short bf16x8;
typedef __attribute__((ext_vector_type(4))) float f32x4;
#define MFMA16(a, b, c) __builtin_amdgcn_mfma_f32_16x16x32_bf16(a, b, c, 0, 0, 0)

__device__ __forceinline__ short bf16_rne(float f) {
    unsigned u = __float_as_uint(f);
    u += 0x7FFFu + ((u >> 16) & 1u);
    return (short)(u >> 16);
}
__device__ __forceinline__ float bf16_to_f(short h) {
    return __uint_as_float(((unsigned)(unsigned short)h) << 16);
}
__device__ __forceinline__ void cvt8(float4 f0, float4 f1,
                                     bf16x8& hi, bf16x8& lo) {
    float v[8] = {f0.x, f0.y, f0.z, f0.w, f1.x, f1.y, f1.z, f1.w};
    #pragma unroll
    for (int j = 0; j < 8; ++j) {
        short h = bf16_rne(v[j]);
        hi[j] = h;
        lo[j] = bf16_rne(v[j] - bf16_to_f(h));
    }
}

__global__ __launch_bounds__(512) void gemm_fused_kernel(
    const float* __restrict__ feat, const float* __restrict__ W_self,
    const float* __restrict__ W_neigh, const float* __restrict__ b_self,
    const float* __restrict__ b_neigh, float* __restrict__ out,
    __hip_bfloat16* __restrict__ g)
{
    int tid = threadIdx.x;
    int lane = tid & 63;
    int wave = tid >> 6;
    int llo = lane & 15;                // A row / B col / C col (within tile)
    int lhi = lane >> 4;                // k-group
    int rb = blockIdx.x * 128 + wave * 16;
    if (rb >= N_NODES) return;          // wave-uniform, no barriers in kernel

    // A fragments: rows rb+llo, k = s*32 + lhi*8 + j  (2 K-steps of 32)
    int arow = rb + llo;
    if (arow > N_NODES - 1) arow = N_NODES - 1;   // tail clamp (stores guarded)
    const float4* fr = (const float4*)(feat + (size_t)arow * D);
    bf16x8 ahi[2], alo[2];
    #pragma unroll
    for (int s = 0; s < 2; ++s)
        cvt8(fr[s * 8 + lhi * 2], fr[s * 8 + lhi * 2 + 1], ahi[s], alo[s]);

    unsigned short* g16 = (unsigned short*)g;
    #pragma unroll
    for (int nt = 0; nt < 4; ++nt) {    // 4 N-tiles of 16 cols
        int col = nt * 16 + llo;
        const float4* ws = (const float4*)(W_self + (size_t)col * D);
        const float4* wn = (const float4*)(W_neigh + (size_t)col * D);
        f32x4 accS = {0.f, 0.f, 0.f, 0.f};
        f32x4 accN = {0.f, 0.f, 0.f, 0.f};
        #pragma unroll
        for (int s = 0; s < 2; ++s) {
            bf16x8 bh, bl;
            cvt8(ws[s * 8 + lhi * 2], ws[s * 8 + lhi * 2 + 1], bh, bl);
            accS = MFMA16(ahi[s], bh, accS);
            accS = MFMA16(alo[s], bh, accS);
            accS = MFMA16(ahi[s], bl, accS);
            cvt8(wn[s * 8 + lhi * 2], wn[s * 8 + lhi * 2 + 1], bh, bl);
            accN = MFMA16(ahi[s], bh, accN);
            accN = MFMA16(alo[s], bh, accN);
            accN = MFMA16(ahi[s], bl, accN);
        }
        float bias = b_self[col] + b_neigh[col];
        #pragma unroll
        for (int rg = 0; rg < 4; ++rg) {
            int r = rb + lhi * 4 + rg;  // C: row=(lane>>4)*4+reg
            if (r < N_NODES) {
                out[(size_t)r * D + col] = accS[rg] + bias;
                g16[(size_t)r * D + col] = (unsigned short)bf16_rne(accN[rg]);
            }
        }
    }
}

// ---------------------------------------------------------------------------
// Aggregation: one wave per node, 16 EDGES PER ITERATION (unroll x4 -> 4
// independent row gathers in flight per 16-lane group; x2 measured 2.57 TB/s
// at 119 MB traffic == running exactly at achieved BW, i.e. MLP-limited, not
// byte-limited). Mean degree = 16, so the x4 body is one iteration for the
// typical node. Lane = 16*q + t: group q handles edges i+q, i+4+q, i+8+q,
// i+12+q; lane t covers features 4t..4t+3 via uint2 (4 bf16). Zero atomics.
// ---------------------------------------------------------------------------
__global__ __launch_bounds__(256) void aggregate_kernel(
    const uint* __restrict__ g32, const unsigned* __restrict__ edata,
    const int* __restrict__ offsets, float* __restrict__ out)
{
    int v = blockIdx.x * 4 + (threadIdx.x >> 6);   // 25000*4 == N exactly
    int lane = threadIdx.x & 63;
    int q = lane >> 4;                 // edge group
    int t = lane & 15;                 // feature quad: features 4t..4t+3
    int lo = offsets[v], hi = offsets[v + 1];
    float4 acc = make_float4(0.f, 0.f, 0.f, 0.f);
    float sum = 0.f;

    for (int i = lo; i < hi; i += 16) {
        int e0 = i + q;
        int e1 = i + 4 + q;
        int e2 = i + 8 + q;
        int e3 = i + 12 + q;
        int ec0 = (e0 < hi) ? e0 : hi - 1;         // in-bounds (loop => hi>lo)
        int ec1 = (e1 < hi) ? e1 : hi - 1;
        int ec2 = (e2 < hi) ? e2 : hi - 1;
        int ec3 = (e3 < hi) ? e3 : hi - 1;
        unsigned p0 = edata[ec0];                  // coalesced, L2-hot
        unsigned p1 = edata[ec1];
        unsigned p2 = edata[ec2];
        unsigned p3 = edata[ec3];
        float w0 = (e0 < hi) ? __uint_as_float((p0 & 0x7FFFu) << 16) : 0.f;
        float w1 = (e1 < hi) ? __uint_as_float((p1 & 0x7FFFu) << 16) : 0.f;
        float w2 = (e2 < hi) ? __uint_as_float((p2 & 0x7FFFu) << 16) : 0.f;
        float w3 = (e3 < hi) ? __uint_as_float((p3 & 0x7FFFu) << 16) : 0.f;
        const uint2* r0 = (const uint2*)(g32 + (size_t)(p0 >> 15) * (D / 2));
        const uint2* r1 = (const uint2*)(g32 + (size_t)(p1 >> 15) * (D / 2));
        const uint2* r2 = (const uint2*)(g32 + (size_t)(p2 >> 15) * (D / 2));
        const uint2* r3 = (const uint2*)(g32 + (size_t)(p3 >> 15) * (D / 2));
        uint2 u0 = r0[t];                          // 4 gathers in flight
        uint2 u1 = r1[t];
        uint2 u2 = r2[t];
        uint2 u3 = r3[t];
        acc.x += w0 * __uint_as_float(u0.x << 16);
        acc.y += w0 * __uint_as_float(u0.x & 0xFFFF0000u);
        acc.z += w0 * __uint_as_float(u0.y << 16);
        acc.w += w0 * __uint_as_float(u0.y & 0xFFFF0000u);
        sum += w0;
        acc.x += w1 * __uint_as_float(u1.x << 16);
        acc.y += w1 * __uint_as_float(u1.x & 0xFFFF0000u);
        acc.z += w1 * __uint_as_float(u1.y << 16);
        acc.w += w1 * __uint_as_float(u1.y & 0xFFFF0000u);
        sum += w1;
        acc.x += w2 * __uint_as_float(u2.x << 16);
        acc.y += w2 * __uint_as_float(u2.x & 0xFFFF0000u);
        acc.z += w2 * __uint_as_float(u2.y << 16);
        acc.w += w2 * __uint_as_float(u2.y & 0xFFFF0000u);
        sum += w2;
        acc.x += w3 * __uint_as_float(u3.x << 16);
        acc.y += w3 * __uint_as_float(u3.x & 0xFFFF0000u);
        acc.z += w3 * __uint_as_float(u3.y << 16);
        acc.w += w3 * __uint_as_float(u3.y & 0xFFFF0000u);
        sum += w3;
    }
    // combine the 4 groups (each lane t holds partials for feats 4t..4t+3)
    #pragma unroll
    for (int mm = 16; mm <= 32; mm <<= 1) {
        acc.x += __shfl_xor(acc.x, mm, 64);
        acc.y += __shfl_xor(acc.y, mm, 64);
        acc.z += __shfl_xor(acc.z, mm, 64);
        acc.w += __shfl_xor(acc.w, mm, 64);
        sum   += __shfl_xor(sum,   mm, 64);
    }
    if (hi > lo && q == 0) {                       // 16 lanes: float4 each
        float inv = 1.f / sum;
        float4* orow = (float4*)(out + (size_t)v * D);
        float4 c = orow[t];
        c.x += acc.x * inv; c.y += acc.y * inv;
        c.z += acc.z * inv; c.w += acc.w * inv;
        orow[t] = c;
    }
    // zero-degree nodes: reference gives h_neigh = 0 -> out keeps self part
}

// ---------------------------------------------------------------------------
extern "C" void kernel_launch(void* const* d_in, const int* in_sizes, int n_in,
                              void* d_out, int out_size, void* d_ws, size_t ws_size,
                              hipStream_t stream) {
    const float* feat    = (const float*)d_in[0];
    const float* rel     = (const float*)d_in[1];
    const float* W_self  = (const float*)d_in[2];
    const float* b_self  = (const float*)d_in[3];
    const float* W_neigh = (const float*)d_in[4];
    const float* b_neigh = (const float*)d_in[5];
    const float* attn_e  = (const float*)d_in[6];
    const int*   src     = (const int*)d_in[7];
    const int*   dst     = (const int*)d_in[8];
    float* out = (float*)d_out;

    // workspace layout (~33.3 MB)
    uint2* binned = (uint2*)d_ws;                               // 13.65 MB
    __hip_bfloat16* g = (__hip_bfloat16*)(binned + (size_t)NBUCK * BUCKET_CAP); // 12.8 MB
    unsigned* edata = (unsigned*)((char*)g + (size_t)N_NODES * D * 2);  // 6.4 MB
    int* offsets = (int*)(edata + N_EDGES);                     // [N+1]
    int* bucket_cursor = offsets + N_NODES + 1;                 // [NBUCK]

    hipMemsetAsync(bucket_cursor, 0, NBUCK * sizeof(int), stream);

    binning_kernel<<<(N_EDGES + P1_EPB - 1) / P1_EPB, P1_T, 0, stream>>>(
        (const float2*)rel, attn_e, src, dst, bucket_cursor, binned);
    csr_kernel<<<NBUCK, 1024, 0, stream>>>(
        bucket_cursor, binned, offsets, edata);
    gemm_fused_kernel<<<(N_NODES + 127) / 128, 512, 0, stream>>>(
        feat, W_self, W_neigh, b_self, b_neigh, out, g);
    aggregate_kernel<<<N_NODES / 4, 256, 0, stream>>>(
        (const uint*)g, edata, offsets, out);
}

// Round 2
// 189.823 us; speedup vs baseline: 1.1332x; 1.0894x over previous
//
#include <hip/hip_runtime.h>
#include <hip/hip_bf16.h>

#define N_NODES 100000
#define N_EDGES 1600000
#define D 64
#define NEG_SLOPE 0.2f

#define BSHIFT 9                                   // bucket = dst >> 9
#define BNODES 512                                 // nodes per bucket
#define NBUCK ((N_NODES + BNODES - 1) >> BSHIFT)   // 196
#define BUCKET_CAP 8896    // mean 8192, sigma ~90 -> ~8-sigma headroom
#define P1_EPB 4096        // edges per binning block
#define P1_T 512
#define P1_IT (P1_EPB / P1_T)                      // 8 edges/thread
#define GRID_BIN ((N_EDGES + P1_EPB - 1) / P1_EPB) // 391

typedef __attribute__((ext_vector_type(8))) short bf16x8;
typedef __attribute__((ext_vector_type(4))) float f32x4;
#define MFMA16(a, b, c) __builtin_amdgcn_mfma_f32_16x16x32_bf16(a, b, c, 0, 0, 0)

__device__ __forceinline__ short bf16_rne(float f) {
    unsigned u = __float_as_uint(f);
    u += 0x7FFFu + ((u >> 16) & 1u);
    return (short)(u >> 16);
}
__device__ __forceinline__ float bf16_to_f(short h) {
    return __uint_as_float(((unsigned)(unsigned short)h) << 16);
}
// split fp32 -> hi + lo bf16 (two RNE roundings): A@B ~= Ah@Bh + Al@Bh + Ah@Bl
__device__ __forceinline__ void cvt8(float4 f0, float4 f1,
                                     bf16x8& hi, bf16x8& lo) {
    float v[8] = {f0.x, f0.y, f0.z, f0.w, f1.x, f1.y, f1.z, f1.w};
    #pragma unroll
    for (int j = 0; j < 8; ++j) {
        short h = bf16_rne(v[j]);
        hi[j] = h;
        lo[j] = bf16_rne(v[j] - bf16_to_f(h));
    }
}

// ---------------------------------------------------------------------------
// Pass 1: bin edges by coarse dst bucket, LDS-staged so ALL global writes are
// coalesced runs. Entry: {x = (src<<15)|wcode (bf16 weight, sign dropped),
// y = dst}. Block GRID_BIN is a bolt-on W-FRAGMENT PREP block: converts
// W_self/W_neigh to hi/lo bf16x8 MFMA A-fragments ONCE (round-1 gemm did
// this per-thread x782 blocks -- 900 redundant VALU ops on the critical
// load->cvt->mfma chain, MfmaUtil 4%, all pipes <25%).
// segment_max skipped: softmax is shift-invariant and |e| <= |a0|+|a1| is
// tiny, so exp() cannot overflow -- identical math to the reference.
// ---------------------------------------------------------------------------
__global__ __launch_bounds__(P1_T) void binning_kernel(
    const float2* __restrict__ rel, const float* __restrict__ attn_e,
    const int* __restrict__ src, const int* __restrict__ dst,
    int* __restrict__ bucket_cursor, uint2* __restrict__ binned,
    const float* __restrict__ W_self, const float* __restrict__ W_neigh,
    const float* __restrict__ b_self, const float* __restrict__ b_neigh,
    bf16x8* __restrict__ wfrag, float* __restrict__ bsum)
{
    __shared__ uint2 staged1[P1_EPB];   // arrival order      (32 KB)
    __shared__ uint2 staged2[P1_EPB];   // bucket-sorted      (32 KB)
    __shared__ int cnt[NBUCK];
    __shared__ int excl[NBUCK];
    __shared__ int chunkbase[NBUCK];

    int tid = threadIdx.x;

    if (blockIdx.x == GRID_BIN) {       // W prep: 1024 (nt,mat,s,lane) combos
        if (tid < D) bsum[tid] = b_self[tid] + b_neigh[tid];
        for (int c = tid; c < 1024; c += P1_T) {
            int nt = c >> 8;                       // output-feature tile
            int mat = (c >> 7) & 1;                // 0=self 1=neigh
            int s = (c >> 6) & 1;                  // K-step
            int lane = c & 63;
            const float* Wm = mat ? W_neigh : W_self;
            int row = nt * 16 + (lane & 15);       // A-row = output feature
            int koff = s * 32 + (lane >> 4) * 8;   // k = (lane>>4)*8 + j
            const float4* p = (const float4*)(Wm + row * D + koff);
            bf16x8 hi, lo;
            cvt8(p[0], p[1], hi, lo);
            int base = (c >> 6) * 128 + (c & 63);  // (nt*4+mat*2+s)*128+lane
            wfrag[base] = hi;
            wfrag[base + 64] = lo;
        }
        return;
    }

    int e0 = blockIdx.x * P1_EPB;
    int n = min(P1_EPB, N_EDGES - e0);

    for (int b = tid; b < NBUCK; b += P1_T) cnt[b] = 0;
    __syncthreads();

    float a0 = attn_e[0], a1 = attn_e[1];

    int myslot[P1_IT];                  // fixed-index -> stays in VGPRs
    #pragma unroll
    for (int j = 0; j < P1_IT; ++j) {
        int i = tid + j * P1_T;
        if (i < n) {
            int e = e0 + i;
            float2 r = rel[e];
            float sc = r.x * a0 + r.y * a1;
            sc = (sc > 0.f) ? sc : NEG_SLOPE * sc;
            float ev = __expf(sc);
            unsigned u = __float_as_uint(ev) + 0x8000u;     // RNE to bf16
            unsigned wcode = (u >> 16) & 0x7FFFu;           // drop sign (ev>0)
            unsigned s = (unsigned)src[e];
            unsigned d = (unsigned)dst[e];
            staged1[i] = make_uint2((s << 15) | wcode, d);
            myslot[j] = atomicAdd(&cnt[d >> BSHIFT], 1);    // local ticket
        }
    }
    __syncthreads();
    if (tid == 0) {                     // NBUCK-entry serial scan: trivial
        int run = 0;
        for (int b = 0; b < NBUCK; ++b) { excl[b] = run; run += cnt[b]; }
    }
    __syncthreads();
    #pragma unroll
    for (int j = 0; j < P1_IT; ++j) {   // LDS scatter into bucket order
        int i = tid + j * P1_T;
        if (i < n) {
            uint2 v = staged1[i];
            staged2[excl[v.y >> BSHIFT] + myslot[j]] = v;
        }
    }
    if (tid < NBUCK)                    // reserve contiguous global chunks
        chunkbase[tid] = atomicAdd(&bucket_cursor[tid], cnt[tid]);
    __syncthreads();
    for (int i = tid; i < n; i += P1_T) {  // coalesced runs per bucket chunk
        uint2 v = staged2[i];
        int b = (int)(v.y >> BSHIFT);
        binned[(size_t)b * BUCKET_CAP + chunkbase[b] + (i - excl[b])] = v;
    }
}

// ---------------------------------------------------------------------------
// Pass 2: one block per bucket, 1024 threads. LDS histogram -> LDS scan ->
// write offsets -> LDS scatter of packed values -> coalesced flush.
// BSHIFT 10->9: round-1's 98 blocks x 70KB LDS covered only 38% of the 256
// CUs (grid-coverage-bound, not work-bound); 196 blocks x ~42KB covers 77%.
// ---------------------------------------------------------------------------
__global__ __launch_bounds__(1024) void csr_kernel(
    const int* __restrict__ bucket_cursor, const uint2* __restrict__ binned,
    int* __restrict__ offsets, unsigned* __restrict__ edata)
{
    __shared__ unsigned vals[BUCKET_CAP];   // 35.6 KB
    __shared__ int hist[BNODES];
    __shared__ int nexcl[BNODES];
    __shared__ int cur[BNODES];
    __shared__ int bc[NBUCK];
    __shared__ int base_sh;

    int b = blockIdx.x;
    int tid = threadIdx.x;

    if (tid < NBUCK) bc[tid] = bucket_cursor[tid];
    if (tid < BNODES) { hist[tid] = 0; cur[tid] = 0; }
    __syncthreads();
    if (tid == 0) {
        int s = 0;
        for (int i = 0; i < b; ++i) s += bc[i];
        base_sh = s;
    }
    __syncthreads();
    int count = bc[b];
    int base = base_sh;
    const uint2* bin = binned + (size_t)b * BUCKET_CAP;

    for (int i = tid; i < count; i += 1024)
        atomicAdd(&hist[bin[i].y & (BNODES - 1)], 1);
    __syncthreads();

    // inclusive Hillis-Steele over BNODES bins, one bin per thread
    int h = 0;
    if (tid < BNODES) { h = hist[tid]; nexcl[tid] = h; }
    __syncthreads();
    for (int d = 1; d < BNODES; d <<= 1) {
        int u = (tid >= d && tid < BNODES) ? nexcl[tid - d] : 0;
        __syncthreads();
        if (tid < BNODES) nexcl[tid] += u;
        __syncthreads();
    }
    int excl = 0;
    if (tid < BNODES) excl = nexcl[tid] - h;       // exclusive prefix
    __syncthreads();
    if (tid < BNODES) nexcl[tid] = excl;
    __syncthreads();

    int node = (b << BSHIFT) + tid;
    if (tid < BNODES && node < N_NODES) offsets[node] = base + excl;
    if (b == NBUCK - 1 && tid == 0) offsets[N_NODES] = N_EDGES;

    for (int i = tid; i < count; i += 1024) {     // LDS scatter
        uint2 e = bin[i];
        int d = e.y & (BNODES - 1);
        int t = atomicAdd(&cur[d], 1);
        vals[nexcl[d] + t] = e.x;
    }
    __syncthreads();
    for (int i = tid; i < count; i += 1024)       // coalesced flush
        edata[base + i] = vals[i];
}

// ---------------------------------------------------------------------------
// FUSED GEMM v3. Operand roles SWAPPED vs round-1: A = precomputed W frags
// (A-row = output feature), B = feat (B-col = node). D-mapping col=lane&15,
// row=(lane>>4)*4+reg then puts 4 CONSECUTIVE FEATURES of ONE NODE in each
// lane -> float4 stores for out, 8B stores for g (round-1 scattered 16-col
// runs: WRITE_SIZE 49 MB for a 38.4 MB ideal). W fragments are pure 16B
// coalesced loads (L2-hot 32KB) -- no per-thread cvt chain. 256 thr = 4
// waves x 16 nodes; no LDS, no barriers.
// ---------------------------------------------------------------------------
__global__ __launch_bounds__(256) void gemm_fused_kernel(
    const float* __restrict__ feat, const bf16x8* __restrict__ wfrag,
    const float* __restrict__ bsum, float* __restrict__ out,
    __hip_bfloat16* __restrict__ g)
{
    int tid = threadIdx.x;
    int lane = tid & 63;
    int wave = tid >> 6;
    int llo = lane & 15;                // B col = node within tile
    int lhi = lane >> 4;                // k-group / C row-group
    int rb = blockIdx.x * 64 + wave * 16;
    if (rb >= N_NODES) return;          // no barriers in kernel -> safe

    int node = rb + llo;
    bool valid = node < N_NODES;
    int nclamp = valid ? node : N_NODES - 1;       // tail clamp (stores guarded)
    const float4* fr = (const float4*)(feat + (size_t)nclamp * D);
    bf16x8 fhi[2], flo[2];                         // B frags: k=(lane>>4)*8+j
    #pragma unroll
    for (int s = 0; s < 2; ++s)
        cvt8(fr[s * 8 + lhi * 2], fr[s * 8 + lhi * 2 + 1], fhi[s], flo[s]);

    const float4* bs4 = (const float4*)bsum;
    unsigned short* g16 = (unsigned short*)g;

    #pragma unroll
    for (int nt = 0; nt < 4; ++nt) {    // 4 output-feature tiles of 16
        int base = nt * 512 + lane;     // (nt*4+mat*2+s)*128 + h*64 + lane
        bf16x8 wSh0 = wfrag[base];
        bf16x8 wSl0 = wfrag[base + 64];
        bf16x8 wSh1 = wfrag[base + 128];
        bf16x8 wSl1 = wfrag[base + 192];
        bf16x8 wNh0 = wfrag[base + 256];
        bf16x8 wNl0 = wfrag[base + 320];
        bf16x8 wNh1 = wfrag[base + 384];
        bf16x8 wNl1 = wfrag[base + 448];
        f32x4 accS = {0.f, 0.f, 0.f, 0.f};
        f32x4 accN = {0.f, 0.f, 0.f, 0.f};
        accS = MFMA16(wSh0, fhi[0], accS);
        accN = MFMA16(wNh0, fhi[0], accN);
        accS = MFMA16(wSl0, fhi[0], accS);
        accN = MFMA16(wNl0, fhi[0], accN);
        accS = MFMA16(wSh0, flo[0], accS);
        accN = MFMA16(wNh0, flo[0], accN);
        accS = MFMA16(wSh1, fhi[1], accS);
        accN = MFMA16(wNh1, fhi[1], accN);
        accS = MFMA16(wSl1, fhi[1], accS);
        accN = MFMA16(wNl1, fhi[1], accN);
        accS = MFMA16(wSh1, flo[1], accS);
        accN = MFMA16(wNh1, flo[1], accN);

        if (valid) {
            float4 bb = bs4[nt * 4 + lhi];
            float4 o;
            o.x = accS[0] + bb.x;
            o.y = accS[1] + bb.y;
            o.z = accS[2] + bb.z;
            o.w = accS[3] + bb.w;
            *(float4*)(out + (size_t)node * D + nt * 16 + lhi * 4) = o;
            uint2 gp;
            gp.x = (unsigned)(unsigned short)bf16_rne(accN[0])
                 | ((unsigned)(unsigned short)bf16_rne(accN[1]) << 16);
            gp.y = (unsigned)(unsigned short)bf16_rne(accN[2])
                 | ((unsigned)(unsigned short)bf16_rne(accN[3]) << 16);
            *(uint2*)(g16 + (size_t)node * D + nt * 16 + lhi * 4) = gp;
        }
    }
}

// ---------------------------------------------------------------------------
// Aggregation: one wave per node, 16 EDGES PER ITERATION (unroll x4 -> 4
// independent row gathers in flight per 16-lane group). Mean degree = 16,
// so the x4 body is one iteration for the typical node. Lane = 16*q + t:
// group q handles edges i+q, i+4+q, i+8+q, i+12+q; lane t covers features
// 4t..4t+3 via uint2 (4 bf16). Zero atomics.
// ---------------------------------------------------------------------------
__global__ __launch_bounds__(256) void aggregate_kernel(
    const uint* __restrict__ g32, const unsigned* __restrict__ edata,
    const int* __restrict__ offsets, float* __restrict__ out)
{
    int v = blockIdx.x * 4 + (threadIdx.x >> 6);   // 25000*4 == N exactly
    int lane = threadIdx.x & 63;
    int q = lane >> 4;                 // edge group
    int t = lane & 15;                 // feature quad: features 4t..4t+3
    int lo = offsets[v], hi = offsets[v + 1];
    float4 acc = make_float4(0.f, 0.f, 0.f, 0.f);
    float sum = 0.f;

    for (int i = lo; i < hi; i += 16) {
        int e0 = i + q;
        int e1 = i + 4 + q;
        int e2 = i + 8 + q;
        int e3 = i + 12 + q;
        int ec0 = (e0 < hi) ? e0 : hi - 1;         // in-bounds (loop => hi>lo)
        int ec1 = (e1 < hi) ? e1 : hi - 1;
        int ec2 = (e2 < hi) ? e2 : hi - 1;
        int ec3 = (e3 < hi) ? e3 : hi - 1;
        unsigned p0 = edata[ec0];                  // coalesced, L2-hot
        unsigned p1 = edata[ec1];
        unsigned p2 = edata[ec2];
        unsigned p3 = edata[ec3];
        float w0 = (e0 < hi) ? __uint_as_float((p0 & 0x7FFFu) << 16) : 0.f;
        float w1 = (e1 < hi) ? __uint_as_float((p1 & 0x7FFFu) << 16) : 0.f;
        float w2 = (e2 < hi) ? __uint_as_float((p2 & 0x7FFFu) << 16) : 0.f;
        float w3 = (e3 < hi) ? __uint_as_float((p3 & 0x7FFFu) << 16) : 0.f;
        const uint2* r0 = (const uint2*)(g32 + (size_t)(p0 >> 15) * (D / 2));
        const uint2* r1 = (const uint2*)(g32 + (size_t)(p1 >> 15) * (D / 2));
        const uint2* r2 = (const uint2*)(g32 + (size_t)(p2 >> 15) * (D / 2));
        const uint2* r3 = (const uint2*)(g32 + (size_t)(p3 >> 15) * (D / 2));
        uint2 u0 = r0[t];                          // 4 gathers in flight
        uint2 u1 = r1[t];
        uint2 u2 = r2[t];
        uint2 u3 = r3[t];
        acc.x += w0 * __uint_as_float(u0.x << 16);
        acc.y += w0 * __uint_as_float(u0.x & 0xFFFF0000u);
        acc.z += w0 * __uint_as_float(u0.y << 16);
        acc.w += w0 * __uint_as_float(u0.y & 0xFFFF0000u);
        sum += w0;
        acc.x += w1 * __uint_as_float(u1.x << 16);
        acc.y += w1 * __uint_as_float(u1.x & 0xFFFF0000u);
        acc.z += w1 * __uint_as_float(u1.y << 16);
        acc.w += w1 * __uint_as_float(u1.y & 0xFFFF0000u);
        sum += w1;
        acc.x += w2 * __uint_as_float(u2.x << 16);
        acc.y += w2 * __uint_as_float(u2.x & 0xFFFF0000u);
        acc.z += w2 * __uint_as_float(u2.y << 16);
        acc.w += w2 * __uint_as_float(u2.y & 0xFFFF0000u);
        sum += w2;
        acc.x += w3 * __uint_as_float(u3.x << 16);
        acc.y += w3 * __uint_as_float(u3.x & 0xFFFF0000u);
        acc.z += w3 * __uint_as_float(u3.y << 16);
        acc.w += w3 * __uint_as_float(u3.y & 0xFFFF0000u);
        sum += w3;
    }
    // combine the 4 groups (each lane t holds partials for feats 4t..4t+3)
    #pragma unroll
    for (int mm = 16; mm <= 32; mm <<= 1) {
        acc.x += __shfl_xor(acc.x, mm, 64);
        acc.y += __shfl_xor(acc.y, mm, 64);
        acc.z += __shfl_xor(acc.z, mm, 64);
        acc.w += __shfl_xor(acc.w, mm, 64);
        sum   += __shfl_xor(sum,   mm, 64);
    }
    if (hi > lo && q == 0) {                       // 16 lanes: float4 each
        float inv = 1.f / sum;
        float4* orow = (float4*)(out + (size_t)v * D);
        float4 c = orow[t];
        c.x += acc.x * inv; c.y += acc.y * inv;
        c.z += acc.z * inv; c.w += acc.w * inv;
        orow[t] = c;
    }
    // zero-degree nodes: reference gives h_neigh = 0 -> out keeps self part
}

// ---------------------------------------------------------------------------
extern "C" void kernel_launch(void* const* d_in, const int* in_sizes, int n_in,
                              void* d_out, int out_size, void* d_ws, size_t ws_size,
                              hipStream_t stream) {
    const float* feat    = (const float*)d_in[0];
    const float* rel     = (const float*)d_in[1];
    const float* W_self  = (const float*)d_in[2];
    const float* b_self  = (const float*)d_in[3];
    const float* W_neigh = (const float*)d_in[4];
    const float* b_neigh = (const float*)d_in[5];
    const float* attn_e  = (const float*)d_in[6];
    const int*   src     = (const int*)d_in[7];
    const int*   dst     = (const int*)d_in[8];
    float* out = (float*)d_out;

    // workspace layout (~33.6 MB), all segments 16B-aligned
    uint2* binned = (uint2*)d_ws;                               // 13.95 MB
    __hip_bfloat16* g = (__hip_bfloat16*)(binned + (size_t)NBUCK * BUCKET_CAP); // 12.8 MB
    unsigned* edata = (unsigned*)((char*)g + (size_t)N_NODES * D * 2);  // 6.4 MB
    bf16x8* wfrag = (bf16x8*)(edata + N_EDGES);                 // 32 KB
    float* bsum = (float*)(wfrag + 2048);                       // 256 B
    int* offsets = (int*)(bsum + 64);                           // [N+1]
    int* bucket_cursor = offsets + N_NODES + 1;                 // [NBUCK]

    hipMemsetAsync(bucket_cursor, 0, NBUCK * sizeof(int), stream);

    binning_kernel<<<GRID_BIN + 1, P1_T, 0, stream>>>(
        (const float2*)rel, attn_e, src, dst, bucket_cursor, binned,
        W_self, W_neigh, b_self, b_neigh, wfrag, bsum);
    csr_kernel<<<NBUCK, 1024, 0, stream>>>(
        bucket_cursor, binned, offsets, edata);
    gemm_fused_kernel<<<(N_NODES + 63) / 64, 256, 0, stream>>>(
        feat, wfrag, bsum, out, g);
    aggregate_kernel<<<N_NODES / 4, 256, 0, stream>>>(
        (const uint*)g, edata, offsets, out);
}

// Round 3
// 177.836 us; speedup vs baseline: 1.2096x; 1.0674x over previous
//
#include <hip/hip_runtime.h>
#include <hip/hip_bf16.h>
#include <hip/hip_fp16.h>

#define N_NODES 100000
#define N_EDGES 1600000
#define D 64
#define NEG_SLOPE 0.2f

#define BSHIFT 9                                   // bucket = dst >> 9
#define BNODES 512                                 // nodes per bucket
#define NBUCK ((N_NODES + BNODES - 1) >> BSHIFT)   // 196
#define BUCKET_CAP 8896    // mean 8192, sigma ~90 -> ~8-sigma headroom
#define P1_EPB 4096        // edges per binning block
#define P1_T 512
#define P1_IT (P1_EPB / P1_T)                      // 8 edges/thread
#define GRID_BIN ((N_EDGES + P1_EPB - 1) / P1_EPB) // 391
#define GEMM_BLKS ((N_NODES + 127) / 128)          // 782

typedef __attribute__((ext_vector_type(8))) short bf16x8;
typedef __attribute__((ext_vector_type(4))) float f32x4;
#define MFMA16(a, b, c) __builtin_amdgcn_mfma_f32_16x16x32_bf16(a, b, c, 0, 0, 0)

__device__ __forceinline__ short bf16_rne(float f) {
    unsigned u = __float_as_uint(f);
    u += 0x7FFFu + ((u >> 16) & 1u);
    return (short)(u >> 16);
}
__device__ __forceinline__ float bf16_to_f(short h) {
    return __uint_as_float(((unsigned)(unsigned short)h) << 16);
}
// split fp32 -> hi + lo bf16 (two RNE roundings): A@B ~= Ah@Bh + Al@Bh + Ah@Bl
__device__ __forceinline__ void cvt8(float4 f0, float4 f1,
                                     bf16x8& hi, bf16x8& lo) {
    float v[8] = {f0.x, f0.y, f0.z, f0.w, f1.x, f1.y, f1.z, f1.w};
    #pragma unroll
    for (int j = 0; j < 8; ++j) {
        short h = bf16_rne(v[j]);
        hi[j] = h;
        lo[j] = bf16_rne(v[j] - bf16_to_f(h));
    }
}

// shared-memory overlay (union of the two block roles; raw bytes to avoid
// ctor issues). bin: staged1 32K | staged2 32K | cnt/excl/chunkbase 3x784 |
// wtot 16. gemm: wfrag 32K | bsum 256.
#define SM_BYTES 67904

// ---------------------------------------------------------------------------
// FUSED binning + GEMM kernel. Blocks [0, GRID_BIN): bin edges by coarse dst
// bucket (LDS-staged so all global writes are coalesced runs). Blocks
// [GRID_BIN, GRID_BIN+GEMM_BLKS): MFMA GEMM, 128 nodes/block. The two chains
// are data-independent -- fusing removes a serialized launch (~gemm's whole
// duration) since gemm compute packs into binning's memory/LDS-wait slack.
// Each gemm block preps W hi/lo-bf16 MFMA fragments cooperatively in LDS
// (no cross-block ordering dependence, unlike a global wfrag producer).
// segment_max skipped: softmax is shift-invariant and |e| <= |a0|+|a1| is
// tiny, so exp() cannot overflow -- identical math to the reference.
// ---------------------------------------------------------------------------
__global__ __launch_bounds__(P1_T) void fused_bin_gemm_kernel(
    const float2* __restrict__ rel, const float* __restrict__ attn_e,
    const int* __restrict__ src, const int* __restrict__ dst,
    int* __restrict__ bucket_cursor, uint2* __restrict__ binned,
    const float* __restrict__ feat,
    const float* __restrict__ W_self, const float* __restrict__ W_neigh,
    const float* __restrict__ b_self, const float* __restrict__ b_neigh,
    float* __restrict__ out, __half* __restrict__ g)
{
    __shared__ __align__(16) char smem[SM_BYTES];
    int tid = threadIdx.x;

    if (blockIdx.x >= GRID_BIN) {
        // ---------------- GEMM role ----------------
        bf16x8* wfrag = (bf16x8*)smem;              // 2048 frags, 32 KB
        float* bsum = (float*)(smem + 32768);       // 64 floats
        if (tid < D) bsum[tid] = b_self[tid] + b_neigh[tid];
        for (int c = tid; c < 1024; c += P1_T) {    // W prep, once per block
            int nt = c >> 8;                        // output-feature tile
            int mat = (c >> 7) & 1;                 // 0=self 1=neigh
            int s = (c >> 6) & 1;                   // K-step
            int ln = c & 63;
            const float* Wm = mat ? W_neigh : W_self;
            int row = nt * 16 + (ln & 15);          // A-row = output feature
            int koff = s * 32 + (ln >> 4) * 8;      // k = (lane>>4)*8 + j
            const float4* p = (const float4*)(Wm + row * D + koff);
            bf16x8 hi, lo;
            cvt8(p[0], p[1], hi, lo);
            int base = (c >> 6) * 128 + ln;         // (nt*4+mat*2+s)*128+lane
            wfrag[base] = hi;
            wfrag[base + 64] = lo;
        }
        __syncthreads();

        int lane = tid & 63;
        int wave = tid >> 6;
        int llo = lane & 15;            // B col = node within tile
        int lhi = lane >> 4;            // k-group / C row-group
        int rb = (blockIdx.x - GRID_BIN) * 128 + wave * 16;
        if (rb >= N_NODES) return;      // after the only barrier -> safe

        int node = rb + llo;
        bool valid = node < N_NODES;
        int nclamp = valid ? node : N_NODES - 1;    // tail clamp
        const float4* fr = (const float4*)(feat + (size_t)nclamp * D);
        bf16x8 fhi[2], flo[2];                      // B frags: k=(lhi)*8+j
        #pragma unroll
        for (int s = 0; s < 2; ++s)
            cvt8(fr[s * 8 + lhi * 2], fr[s * 8 + lhi * 2 + 1], fhi[s], flo[s]);

        const float4* bs4 = (const float4*)bsum;
        #pragma unroll
        for (int nt = 0; nt < 4; ++nt) {            // 4 out-feature tiles
            int base = nt * 512 + lane;
            bf16x8 wSh0 = wfrag[base];
            bf16x8 wSl0 = wfrag[base + 64];
            bf16x8 wSh1 = wfrag[base + 128];
            bf16x8 wSl1 = wfrag[base + 192];
            bf16x8 wNh0 = wfrag[base + 256];
            bf16x8 wNl0 = wfrag[base + 320];
            bf16x8 wNh1 = wfrag[base + 384];
            bf16x8 wNl1 = wfrag[base + 448];
            f32x4 accS = {0.f, 0.f, 0.f, 0.f};
            f32x4 accN = {0.f, 0.f, 0.f, 0.f};
            accS = MFMA16(wSh0, fhi[0], accS);
            accN = MFMA16(wNh0, fhi[0], accN);
            accS = MFMA16(wSl0, fhi[0], accS);
            accN = MFMA16(wNl0, fhi[0], accN);
            accS = MFMA16(wSh0, flo[0], accS);
            accN = MFMA16(wNh0, flo[0], accN);
            accS = MFMA16(wSh1, fhi[1], accS);
            accN = MFMA16(wNh1, fhi[1], accN);
            accS = MFMA16(wSl1, fhi[1], accS);
            accN = MFMA16(wNl1, fhi[1], accN);
            accS = MFMA16(wSh1, flo[1], accS);
            accN = MFMA16(wNh1, flo[1], accN);

            if (valid) {
                float4 bb = bs4[nt * 4 + lhi];
                float4 o;
                o.x = accS[0] + bb.x;
                o.y = accS[1] + bb.y;
                o.z = accS[2] + bb.z;
                o.w = accS[3] + bb.w;
                *(float4*)(out + (size_t)node * D + nt * 16 + lhi * 4) = o;
                // g stored as fp16 (3 more mantissa bits than bf16 AND
                // enables v_fma_mix consumption in aggregate)
                __half2 hA = __floats2half2_rn(accN[0], accN[1]);
                __half2 hB = __floats2half2_rn(accN[2], accN[3]);
                uint2 gp = make_uint2(*(unsigned*)&hA, *(unsigned*)&hB);
                *(uint2*)(g + (size_t)node * D + nt * 16 + lhi * 4) = gp;
            }
        }
        return;
    }

    // ---------------- binning role ----------------
    uint2* staged1 = (uint2*)smem;                  // arrival order (32 KB)
    uint2* staged2 = (uint2*)(smem + 32768);        // bucket-sorted (32 KB)
    int* cnt = (int*)(smem + 65536);
    int* excl = (int*)(smem + 65536 + 784);
    int* chunkbase = (int*)(smem + 65536 + 1568);
    int* wtot = (int*)(smem + 65536 + 2352);

    int e0 = blockIdx.x * P1_EPB;
    int n = min(P1_EPB, N_EDGES - e0);

    for (int b = tid; b < NBUCK; b += P1_T) cnt[b] = 0;
    __syncthreads();

    float a0 = attn_e[0], a1 = attn_e[1];

    int myslot[P1_IT];                  // fixed-index -> stays in VGPRs
    #pragma unroll
    for (int j = 0; j < P1_IT; ++j) {
        int i = tid + j * P1_T;
        if (i < n) {
            int e = e0 + i;
            float2 r = rel[e];
            float sc = r.x * a0 + r.y * a1;
            sc = (sc > 0.f) ? sc : NEG_SLOPE * sc;
            float ev = __expf(sc);
            unsigned u = __float_as_uint(ev) + 0x8000u;     // RNE to bf16
            unsigned wcode = (u >> 16) & 0x7FFFu;           // drop sign (ev>0)
            unsigned s = (unsigned)src[e];
            unsigned d = (unsigned)dst[e];
            staged1[i] = make_uint2((s << 15) | wcode, d);
            myslot[j] = atomicAdd(&cnt[d >> BSHIFT], 1);    // local ticket
        }
    }
    __syncthreads();
    // wave-shfl exclusive scan of cnt[0..NBUCK) (was: tid0 serial 196-scan)
    {
        int ln = tid & 63, wv = tid >> 6;
        int c = 0;
        if (tid < 256) c = (tid < NBUCK) ? cnt[tid] : 0;
        int x = c;
        #pragma unroll
        for (int dd = 1; dd < 64; dd <<= 1) {
            int y = __shfl_up(x, dd, 64);
            if (ln >= dd) x += y;
        }
        if (tid < 256 && ln == 63) wtot[wv] = x;
        __syncthreads();
        if (tid < NBUCK) {
            int wbase = 0;
            for (int k = 0; k < wv; ++k) wbase += wtot[k];
            excl[tid] = wbase + x - c;
        }
        __syncthreads();
    }
    #pragma unroll
    for (int j = 0; j < P1_IT; ++j) {   // LDS scatter into bucket order
        int i = tid + j * P1_T;
        if (i < n) {
            uint2 v = staged1[i];
            staged2[excl[v.y >> BSHIFT] + myslot[j]] = v;
        }
    }
    if (tid < NBUCK)                    // reserve contiguous global chunks
        chunkbase[tid] = atomicAdd(&bucket_cursor[tid], cnt[tid]);
    __syncthreads();
    for (int i = tid; i < n; i += P1_T) {  // coalesced runs per bucket chunk
        uint2 v = staged2[i];
        int b = (int)(v.y >> BSHIFT);
        binned[(size_t)b * BUCKET_CAP + chunkbase[b] + (i - excl[b])] = v;
    }
}

// ---------------------------------------------------------------------------
// Pass 2: one block per bucket, 1024 threads. LDS histogram -> wave-shfl
// scan (was 9-round Hillis-Steele: 18 barriers -> 2) -> write offsets ->
// LDS scatter of packed values -> coalesced flush.
// ---------------------------------------------------------------------------
__global__ __launch_bounds__(1024) void csr_kernel(
    const int* __restrict__ bucket_cursor, const uint2* __restrict__ binned,
    int* __restrict__ offsets, unsigned* __restrict__ edata)
{
    __shared__ unsigned vals[BUCKET_CAP];   // 35.6 KB
    __shared__ int hist[BNODES];
    __shared__ int nexcl[BNODES];
    __shared__ int cur[BNODES];
    __shared__ int bc[NBUCK];
    __shared__ int wtot[8];
    __shared__ int base_sh;

    int b = blockIdx.x;
    int tid = threadIdx.x;

    if (tid < NBUCK) bc[tid] = bucket_cursor[tid];
    if (tid < BNODES) { hist[tid] = 0; cur[tid] = 0; }
    __syncthreads();
    if (tid == 0) {
        int s = 0;
        for (int i = 0; i < b; ++i) s += bc[i];
        base_sh = s;
    }
    __syncthreads();
    int count = bc[b];
    int base = base_sh;
    const uint2* bin = binned + (size_t)b * BUCKET_CAP;

    for (int i = tid; i < count; i += 1024)
        atomicAdd(&hist[bin[i].y & (BNODES - 1)], 1);
    __syncthreads();

    // wave-shfl scan: waves 0..7 hold one bin per lane
    {
        int ln = tid & 63, wv = tid >> 6;
        int h = 0;
        if (tid < BNODES) h = hist[tid];
        int x = h;
        #pragma unroll
        for (int dd = 1; dd < 64; dd <<= 1) {
            int y = __shfl_up(x, dd, 64);
            if (ln >= dd) x += y;
        }
        if (tid < BNODES && ln == 63) wtot[wv] = x;
        __syncthreads();
        if (tid < BNODES) {
            int wbase = 0;
            for (int k = 0; k < wv; ++k) wbase += wtot[k];
            nexcl[tid] = wbase + x - h;              // exclusive prefix
        }
        __syncthreads();
    }

    int node = (b << BSHIFT) + tid;
    if (tid < BNODES && node < N_NODES) offsets[node] = base + nexcl[tid];
    if (b == NBUCK - 1 && tid == 0) offsets[N_NODES] = N_EDGES;

    for (int i = tid; i < count; i += 1024) {     // LDS scatter
        uint2 e = bin[i];
        int d = e.y & (BNODES - 1);
        int t = atomicAdd(&cur[d], 1);
        vals[nexcl[d] + t] = e.x;
    }
    __syncthreads();
    for (int i = tid; i < count; i += 1024)       // coalesced flush
        edata[base + i] = vals[i];
}

// ---------------------------------------------------------------------------
// Aggregation: one wave per node, fp16 g rows. Lane = 8*q + t: 8 edge groups
// of 8 lanes; lane t covers features 8t..8t+7 via ONE uint4 (8 fp16) --
// halves per-lane edge bookkeeping vs the bf16 uint2 layout, and the
// fmaf(w, (float)half, acc) chain pattern-matches to v_fma_mix_f32 (merged
// cvt+fma; round-2 counters: VALUBusy 59% of a 41.8us kernel with only 36%
// HBM -> VALU was half the critical path). Unroll x2: 16 edges/iter, 2
// outstanding 16B gathers + 2 edata loads per lane. Zero atomics.
// ---------------------------------------------------------------------------
__global__ __launch_bounds__(256) void aggregate_kernel(
    const __half* __restrict__ g, const unsigned* __restrict__ edata,
    const int* __restrict__ offsets, float* __restrict__ out)
{
    int v = blockIdx.x * 4 + (threadIdx.x >> 6);   // 25000*4 == N exactly
    int lane = threadIdx.x & 63;
    int q = lane >> 3;                 // edge group (0..7)
    int t = lane & 7;                  // feature octet: 8t..8t+7
    int lo = offsets[v], hi = offsets[v + 1];
    float4 acc0 = make_float4(0.f, 0.f, 0.f, 0.f);
    float4 acc1 = make_float4(0.f, 0.f, 0.f, 0.f);
    float sum = 0.f;

    for (int i = lo; i < hi; i += 16) {
        int e0 = i + q;
        int e1 = i + 8 + q;
        int ec0 = (e0 < hi) ? e0 : hi - 1;         // in-bounds (loop => hi>lo)
        int ec1 = (e1 < hi) ? e1 : hi - 1;
        unsigned p0 = edata[ec0];                  // coalesced, L2-hot
        unsigned p1 = edata[ec1];
        float w0 = (e0 < hi) ? __uint_as_float((p0 & 0x7FFFu) << 16) : 0.f;
        float w1 = (e1 < hi) ? __uint_as_float((p1 & 0x7FFFu) << 16) : 0.f;
        const uint4* r0 = (const uint4*)(g + (size_t)(p0 >> 15) * D);
        const uint4* r1 = (const uint4*)(g + (size_t)(p1 >> 15) * D);
        uint4 u0 = r0[t];                          // 2x16B gathers in flight
        uint4 u1 = r1[t];
        {
            float2 f;
            f = __half22float2(*(const __half2*)&u0.x);
            acc0.x = fmaf(w0, f.x, acc0.x); acc0.y = fmaf(w0, f.y, acc0.y);
            f = __half22float2(*(const __half2*)&u0.y);
            acc0.z = fmaf(w0, f.x, acc0.z); acc0.w = fmaf(w0, f.y, acc0.w);
            f = __half22float2(*(const __half2*)&u0.z);
            acc1.x = fmaf(w0, f.x, acc1.x); acc1.y = fmaf(w0, f.y, acc1.y);
            f = __half22float2(*(const __half2*)&u0.w);
            acc1.z = fmaf(w0, f.x, acc1.z); acc1.w = fmaf(w0, f.y, acc1.w);
            sum += w0;
        }
        {
            float2 f;
            f = __half22float2(*(const __half2*)&u1.x);
            acc0.x = fmaf(w1, f.x, acc0.x); acc0.y = fmaf(w1, f.y, acc0.y);
            f = __half22float2(*(const __half2*)&u1.y);
            acc0.z = fmaf(w1, f.x, acc0.z); acc0.w = fmaf(w1, f.y, acc0.w);
            f = __half22float2(*(const __half2*)&u1.z);
            acc1.x = fmaf(w1, f.x, acc1.x); acc1.y = fmaf(w1, f.y, acc1.y);
            f = __half22float2(*(const __half2*)&u1.w);
            acc1.z = fmaf(w1, f.x, acc1.z); acc1.w = fmaf(w1, f.y, acc1.w);
            sum += w1;
        }
    }
    // combine the 8 groups (lane t holds partials for feats 8t..8t+7)
    #pragma unroll
    for (int mm = 8; mm <= 32; mm <<= 1) {
        acc0.x += __shfl_xor(acc0.x, mm, 64);
        acc0.y += __shfl_xor(acc0.y, mm, 64);
        acc0.z += __shfl_xor(acc0.z, mm, 64);
        acc0.w += __shfl_xor(acc0.w, mm, 64);
        acc1.x += __shfl_xor(acc1.x, mm, 64);
        acc1.y += __shfl_xor(acc1.y, mm, 64);
        acc1.z += __shfl_xor(acc1.z, mm, 64);
        acc1.w += __shfl_xor(acc1.w, mm, 64);
        sum   += __shfl_xor(sum,   mm, 64);
    }
    if (hi > lo && q == 0) {                       // 8 lanes: 2 float4 each
        float inv = 1.f / sum;
        float4* orow = (float4*)(out + (size_t)v * D);
        float4 c0 = orow[2 * t];
        float4 c1 = orow[2 * t + 1];
        c0.x += acc0.x * inv; c0.y += acc0.y * inv;
        c0.z += acc0.z * inv; c0.w += acc0.w * inv;
        c1.x += acc1.x * inv; c1.y += acc1.y * inv;
        c1.z += acc1.z * inv; c1.w += acc1.w * inv;
        orow[2 * t] = c0;
        orow[2 * t + 1] = c1;
    }
    // zero-degree nodes: reference gives h_neigh = 0 -> out keeps self part
}

// ---------------------------------------------------------------------------
extern "C" void kernel_launch(void* const* d_in, const int* in_sizes, int n_in,
                              void* d_out, int out_size, void* d_ws, size_t ws_size,
                              hipStream_t stream) {
    const float* feat    = (const float*)d_in[0];
    const float* rel     = (const float*)d_in[1];
    const float* W_self  = (const float*)d_in[2];
    const float* b_self  = (const float*)d_in[3];
    const float* W_neigh = (const float*)d_in[4];
    const float* b_neigh = (const float*)d_in[5];
    const float* attn_e  = (const float*)d_in[6];
    const int*   src     = (const int*)d_in[7];
    const int*   dst     = (const int*)d_in[8];
    float* out = (float*)d_out;

    // workspace layout (~33.6 MB), all segments 16B-aligned
    uint2* binned = (uint2*)d_ws;                               // 13.95 MB
    __half* g = (__half*)(binned + (size_t)NBUCK * BUCKET_CAP); // 12.8 MB
    unsigned* edata = (unsigned*)((char*)g + (size_t)N_NODES * D * 2); // 6.4 MB
    int* offsets = (int*)(edata + N_EDGES);                     // [N+1]
    int* bucket_cursor = offsets + N_NODES + 1;                 // [NBUCK]

    hipMemsetAsync(bucket_cursor, 0, NBUCK * sizeof(int), stream);

    fused_bin_gemm_kernel<<<GRID_BIN + GEMM_BLKS, P1_T, 0, stream>>>(
        (const float2*)rel, attn_e, src, dst, bucket_cursor, binned,
        feat, W_self, W_neigh, b_self, b_neigh, out, g);
    csr_kernel<<<NBUCK, 1024, 0, stream>>>(
        bucket_cursor, binned, offsets, edata);
    aggregate_kernel<<<N_NODES / 4, 256, 0, stream>>>(
        g, edata, offsets, out);
}